// Round 1
// 542.589 us; speedup vs baseline: 1.0275x; 1.0275x over previous
//
#include <hip/hip_runtime.h>
#include <stdint.h>

#define E_    16
#define TOPK  2
#define D_    1024
#define H_    1024
#define SH_   2048
#define NTOK  4096
#define BK    32      // K-step (u16 elements); tile rows are 64B -> conflict-free b128 reads
#define NDESC 80      // max expert chunks: 8192/128 + 16 partials
#define RTOK  16      // router tokens per block

typedef unsigned short u16;
typedef __attribute__((ext_vector_type(8))) __bf16 bf16x8;
typedef __attribute__((ext_vector_type(4))) float  f32x4;

__device__ __forceinline__ u16 f2bf(float f) {
  union { float f; unsigned int u; } v; v.f = f;
  unsigned int u = v.u;
  return (u16)((u + 0x7fffu + ((u >> 16) & 1u)) >> 16);   // RN-even
}

// async global->LDS, 16B per lane. LDS dest is wave-uniform base + lane*16
// (hardware rule, learn_hip m104); global src is per-lane (m173) so gather is legal.
__device__ __forceinline__ void gload16(const void* g, void* l) {
  __builtin_amdgcn_global_load_lds(
      (const __attribute__((address_space(1))) unsigned int*)g,
      (__attribute__((address_space(3))) unsigned int*)l, 16, 0, 0);
}

// ---------------- fp32 -> bf16 converter ----------------
__global__ __launch_bounds__(256) void cvt_k(const float* __restrict__ src,
                                             u16* __restrict__ dst) {
  int i = blockIdx.x * 256 + threadIdx.x;      // one float4 per thread
  float4 f = ((const float4*)src)[i];
  ushort4 o; o.x = f2bf(f.x); o.y = f2bf(f.y); o.z = f2bf(f.z); o.w = f2bf(f.w);
  ((ushort4*)dst)[i] = o;
}

// ---------------- router: 16 tokens/block, thread=(expert,token), fp32 ------
__global__ __launch_bounds__(256) void router_k(
    const float* __restrict__ x, const float* __restrict__ gate_w,
    const float* __restrict__ shared_gate_w,
    int* __restrict__ topk_e, float* __restrict__ topk_w,
    float* __restrict__ sg, int* __restrict__ counts) {
  __shared__ float xs[RTOK][132];   // +4 pad: rows offset by 4 banks
  __shared__ float lg[RTOK][16];
  __shared__ float sgp[RTOK][16];

  int tid = threadIdx.x;
  int e   = tid >> 4;               // 0..15
  int tt  = tid & 15;               // 0..15
  int t0  = blockIdx.x * RTOK;

  float acc = 0.f, sga = 0.f;
  for (int c = 0; c < D_; c += 128) {
    __syncthreads();                // xs reuse from previous chunk done
    #pragma unroll
    for (int i = 0; i < 2; i++) {
      int f = i * 256 + tid;        // 0..511 float4 units, fully coalesced
      int r = f >> 5, c4 = f & 31;
      *(float4*)&xs[r][c4 * 4] =
          *(const float4*)&x[(size_t)(t0 + r) * D_ + c + c4 * 4];
    }
    __syncthreads();
    const float* gw = &gate_w[(size_t)e * D_ + c];
    #pragma unroll
    for (int d4 = 0; d4 < 32; d4++) {
      float4 g  = *(const float4*)&gw[d4 * 4];
      float4 xv = *(const float4*)&xs[tt][d4 * 4];
      acc += xv.x * g.x + xv.y * g.y + xv.z * g.z + xv.w * g.w;
    }
    // shared-gate partial: this thread covers d in [e*8, e*8+8)
    #pragma unroll
    for (int j = 0; j < 8; j += 4) {
      float4 s  = *(const float4*)&shared_gate_w[c + e * 8 + j];
      float4 xv = *(const float4*)&xs[tt][e * 8 + j];
      sga += xv.x * s.x + xv.y * s.y + xv.z * s.z + xv.w * s.w;
    }
  }
  lg[tt][e]  = acc;
  sgp[tt][e] = sga;
  __syncthreads();

  if (tid < RTOK) {
    int t = t0 + tid;
    float l[16];
    #pragma unroll
    for (int k = 0; k < 16; k++) l[k] = lg[tid][k];
    int i0 = 0; float l0 = l[0];
    for (int k = 1; k < 16; k++) if (l[k] > l0) { l0 = l[k]; i0 = k; }
    int i1 = -1; float l1 = -3.4e38f;
    for (int k = 0; k < 16; k++) if (k != i0 && l[k] > l1) { l1 = l[k]; i1 = k; }
    float w0 = 1.f / (1.f + expf(l1 - l0));   // == p0/(p0+p1)
    float s = 0.f;
    #pragma unroll
    for (int k = 0; k < 16; k++) s += sgp[tid][k];
    topk_e[2*t] = i0; topk_e[2*t+1] = i1;
    topk_w[2*t] = w0; topk_w[2*t+1] = 1.f - w0;
    sg[t] = 1.f / (1.f + expf(-s));
    atomicAdd(&counts[i0], 1);
    atomicAdd(&counts[i1], 1);
  }
}

// prefix scan + compact chunk-descriptor table (chunk -> expert, m0)
__global__ void scan_k(const int* __restrict__ counts, int* __restrict__ offs,
                       int* __restrict__ desc_e, int* __restrict__ desc_m) {
  if (threadIdx.x == 0) {
    int s = 0, n = 0;
    for (int e = 0; e < E_; e++) {
      offs[e] = s;
      for (int m0 = 0; m0 < counts[e]; m0 += 128) {
        desc_e[n] = e; desc_m[n] = m0; n++;
      }
      s += counts[e];
    }
    offs[E_] = s;
    for (; n < NDESC; n++) { desc_e[n] = -1; desc_m[n] = 0; }
  }
}

__global__ __launch_bounds__(256) void scatter_k(
    const int* __restrict__ topk_e, const float* __restrict__ topk_w,
    const int* __restrict__ offs, int* __restrict__ fill,
    int* __restrict__ tok_of, float* __restrict__ w_of) {
  int t = blockIdx.x * 256 + threadIdx.x;
  if (t >= NTOK) return;
  for (int k = 0; k < TOPK; k++) {
    int e = topk_e[2*t+k];
    int p = atomicAdd(&fill[e], 1);
    int slot = offs[e] + p;
    tok_of[slot] = t;
    w_of[slot]   = topk_w[2*t+k];
  }
}

// ---------------- fused gated up-projection: h = (x@W1^T) * silu(x@Wg^T) ----
// m97-style staging: global_load_lds(16B) direct to LDS, double-buffered,
// ONE barrier per K-step. Tiles are linear [128][BK] (64B rows): exactly
// conflict-free for stride-row ds_read_b128 AND the linear dest the DMA needs.
__global__ __launch_bounds__(256, 2) void up_kernel(
    const u16* __restrict__ Xb,
    const u16* __restrict__ Wg_all, const u16* __restrict__ W1_all,
    u16* __restrict__ Hout, int H,
    const int* __restrict__ tok_of,
    const int* __restrict__ offs, const int* __restrict__ counts,
    const int* __restrict__ desc_e, const int* __restrict__ desc_m) {
  int e, m0, cnt, pbase;
  if (desc_e) {
    e = desc_e[blockIdx.x];
    if (e < 0) return;
    m0 = desc_m[blockIdx.x];
    cnt = counts[e]; pbase = offs[e];
  } else {
    e = 0; m0 = blockIdx.x * 128; cnt = NTOK; pbase = 0;
  }
  int n0 = blockIdx.y * 128;
  const u16* Wg = Wg_all + (size_t)e * H * D_;
  const u16* W1 = W1_all + (size_t)e * H * D_;

  __shared__ u16 smem[2 * 3 * 4096];   // [buf][A,G,U][128*BK]  48KB

  int tid  = threadIdx.x;
  int lane = tid & 63, wave = tid >> 6;
  int wm = wave & 1, wn = wave >> 1;
  int l16 = lane & 15, quad = lane >> 4;

  // staging: wave w owns rows [w*16, w*16+16) (+64 for 2nd issue); lane l
  // lands at wave_base + l*16 bytes = row w*16 + l/4, col (l&3)*8 elems.
  int sr = wave * 16 + (lane >> 2);
  int sc = (lane & 3) * 8;

  int gm0 = m0 + sr;      if (gm0 >= cnt) gm0 = cnt - 1;
  int gm1 = m0 + sr + 64; if (gm1 >= cnt) gm1 = cnt - 1;
  int tok0 = tok_of ? tok_of[pbase + gm0] : gm0;
  int tok1 = tok_of ? tok_of[pbase + gm1] : gm1;
  const u16* pa0 = Xb + (size_t)tok0 * D_ + sc;
  const u16* pa1 = Xb + (size_t)tok1 * D_ + sc;
  const u16* pg0 = Wg + (size_t)(n0 + sr) * D_ + sc;
  const u16* pg1 = pg0 + (size_t)64 * D_;
  const u16* pu0 = W1 + (size_t)(n0 + sr) * D_ + sc;
  const u16* pu1 = pu0 + (size_t)64 * D_;

  int lbase = wave * 512;   // u16 units: wave*1024B within a tile

  f32x4 accg[4][4], accu[4][4];
  f32x4 zero = {0.f, 0.f, 0.f, 0.f};
  #pragma unroll
  for (int i = 0; i < 4; i++)
    #pragma unroll
    for (int j = 0; j < 4; j++) { accg[i][j] = zero; accu[i][j] = zero; }

#define STAGE_UP(b) do {                                            \
    u16* s_ = smem + (b) * 12288 + lbase;                           \
    gload16(pa0, s_);        gload16(pa1, s_ + 2048);               \
    gload16(pg0, s_ + 4096); gload16(pg1, s_ + 6144);               \
    gload16(pu0, s_ + 8192); gload16(pu1, s_ + 10240);              \
    pa0 += BK; pa1 += BK; pg0 += BK; pg1 += BK; pu0 += BK; pu1 += BK; \
  } while (0)

  STAGE_UP(0);
  __syncthreads();            // compiler drains vmcnt(0) before s_barrier
  int buf = 0;

  for (int k0 = 0; k0 < D_; k0 += BK) {
    if (k0 + BK < D_) STAGE_UP(buf ^ 1);   // prefetch next tile into other buf

    const u16* base = smem + buf * 12288;
    bf16x8 af[4], gf[4], uf[4];
    #pragma unroll
    for (int i = 0; i < 4; i++) {
      af[i] = *(const bf16x8*)&base[(wm*64 + i*16 + l16)*BK + quad*8];
      gf[i] = *(const bf16x8*)&base[4096 + (wn*64 + i*16 + l16)*BK + quad*8];
      uf[i] = *(const bf16x8*)&base[8192 + (wn*64 + i*16 + l16)*BK + quad*8];
    }
    #pragma unroll
    for (int i = 0; i < 4; i++)
      #pragma unroll
      for (int j = 0; j < 4; j++) {
        accg[i][j] = __builtin_amdgcn_mfma_f32_16x16x32_bf16(af[i], gf[j], accg[i][j], 0, 0, 0);
        accu[i][j] = __builtin_amdgcn_mfma_f32_16x16x32_bf16(af[i], uf[j], accu[i][j], 0, 0, 0);
      }

    __syncthreads();          // drains next-tile DMA + fences reads of buf
    buf ^= 1;
  }
#undef STAGE_UP

  // epilogue: h = u * silu(g)  (C/D map: col=lane&15, row=quad*4+reg — verified)
  #pragma unroll
  for (int i = 0; i < 4; i++) {
    #pragma unroll
    for (int r = 0; r < 4; r++) {
      int m = m0 + wm*64 + i*16 + quad*4 + r;
      if (m < cnt) {
        size_t prow = (size_t)(pbase + m) * H;
        #pragma unroll
        for (int j = 0; j < 4; j++) {
          int n = n0 + wn*64 + j*16 + l16;
          float g = accg[i][j][r];
          float u = accu[i][j][r];
          Hout[prow + n] = f2bf(u * (g / (1.f + expf(-g))));
        }
      }
    }
  }
}

// ---------------- down-projection: out[tok] (+)= scale * (h @ W2^T) ---------
__global__ __launch_bounds__(256, 3) void down_kernel(
    const u16* __restrict__ Hbuf, int K,
    const u16* __restrict__ W2_all,
    float* __restrict__ out,
    const int* __restrict__ tok_of, const float* __restrict__ scale,
    const int* __restrict__ offs, const int* __restrict__ counts,
    const int* __restrict__ desc_e, const int* __restrict__ desc_m,
    int atomic_mode) {
  int e, m0, cnt, pbase;
  if (desc_e) {
    e = desc_e[blockIdx.x];
    if (e < 0) return;
    m0 = desc_m[blockIdx.x];
    cnt = counts[e]; pbase = offs[e];
  } else {
    e = 0; m0 = blockIdx.x * 128; cnt = NTOK; pbase = 0;
  }
  int n0 = blockIdx.y * 128;
  const u16* W2 = W2_all + (size_t)e * D_ * K;

  __shared__ u16 smem[2 * 2 * 4096];   // [buf][A,B][128*BK]  32KB

  int tid  = threadIdx.x;
  int lane = tid & 63, wave = tid >> 6;
  int wm = wave & 1, wn = wave >> 1;
  int l16 = lane & 15, quad = lane >> 4;

  int sr = wave * 16 + (lane >> 2);
  int sc = (lane & 3) * 8;

  int gm0 = m0 + sr;      if (gm0 >= cnt) gm0 = cnt - 1;
  int gm1 = m0 + sr + 64; if (gm1 >= cnt) gm1 = cnt - 1;
  const u16* pa0 = Hbuf + (size_t)(pbase + gm0) * K + sc;
  const u16* pa1 = Hbuf + (size_t)(pbase + gm1) * K + sc;
  const u16* pb0 = W2 + (size_t)(n0 + sr) * K + sc;
  const u16* pb1 = pb0 + (size_t)64 * K;

  int lbase = wave * 512;

  f32x4 acc[4][4];
  f32x4 zero = {0.f, 0.f, 0.f, 0.f};
  #pragma unroll
  for (int i = 0; i < 4; i++)
    #pragma unroll
    for (int j = 0; j < 4; j++) acc[i][j] = zero;

#define STAGE_DN(b) do {                                \
    u16* s_ = smem + (b) * 8192 + lbase;                \
    gload16(pa0, s_);        gload16(pa1, s_ + 2048);   \
    gload16(pb0, s_ + 4096); gload16(pb1, s_ + 6144);   \
    pa0 += BK; pa1 += BK; pb0 += BK; pb1 += BK;         \
  } while (0)

  STAGE_DN(0);
  __syncthreads();
  int buf = 0;

  for (int k0 = 0; k0 < K; k0 += BK) {
    if (k0 + BK < K) STAGE_DN(buf ^ 1);

    const u16* base = smem + buf * 8192;
    bf16x8 af[4], bfr[4];
    #pragma unroll
    for (int i = 0; i < 4; i++) {
      af[i]  = *(const bf16x8*)&base[(wm*64 + i*16 + l16)*BK + quad*8];
      bfr[i] = *(const bf16x8*)&base[4096 + (wn*64 + i*16 + l16)*BK + quad*8];
    }
    #pragma unroll
    for (int i = 0; i < 4; i++)
      #pragma unroll
      for (int j = 0; j < 4; j++)
        acc[i][j] = __builtin_amdgcn_mfma_f32_16x16x32_bf16(af[i], bfr[j], acc[i][j], 0, 0, 0);

    __syncthreads();
    buf ^= 1;
  }
#undef STAGE_DN

  #pragma unroll
  for (int i = 0; i < 4; i++) {
    #pragma unroll
    for (int r = 0; r < 4; r++) {
      int m = m0 + wm*64 + i*16 + quad*4 + r;
      if (m < cnt) {
        int p   = pbase + m;
        int tok = tok_of ? tok_of[p] : p;
        float sc2 = scale[p];
        if (atomic_mode) {
          #pragma unroll
          for (int j = 0; j < 4; j++) {
            int n = n0 + wn*64 + j*16 + l16;
            atomicAdd(&out[(size_t)tok * D_ + n], sc2 * acc[i][j][r]);
          }
        } else {
          #pragma unroll
          for (int j = 0; j < 4; j++) {
            int n = n0 + wn*64 + j*16 + l16;
            out[(size_t)tok * D_ + n] = sc2 * acc[i][j][r];
          }
        }
      }
    }
  }
}

extern "C" void kernel_launch(void* const* d_in, const int* in_sizes, int n_in,
                              void* d_out, int out_size, void* d_ws, size_t ws_size,
                              hipStream_t stream) {
  const float* x      = (const float*)d_in[0];
  const float* gate_w = (const float*)d_in[1];
  const float* w_gate = (const float*)d_in[2];
  const float* w1     = (const float*)d_in[3];
  const float* w2     = (const float*)d_in[4];
  const float* sh_wg  = (const float*)d_in[5];
  const float* sh_w1  = (const float*)d_in[6];
  const float* sh_w2  = (const float*)d_in[7];
  const float* sh_gw  = (const float*)d_in[8];
  float* out = (float*)d_out;

  char* ws = (char*)d_ws;
  size_t off = 0;
  u16* xb    = (u16*)(ws + off); off += (size_t)NTOK * D_ * 2;
  u16* h_exp = (u16*)(ws + off); off += (size_t)NTOK * TOPK * H_ * 2;
  u16* h_sh  = (u16*)(ws + off); off += (size_t)NTOK * SH_ * 2;
  u16* wb_g  = (u16*)(ws + off); off += (size_t)E_ * H_ * D_ * 2;
  u16* wb_1  = (u16*)(ws + off); off += (size_t)E_ * H_ * D_ * 2;
  u16* wb_2  = (u16*)(ws + off); off += (size_t)E_ * D_ * H_ * 2;
  u16* sb_g  = (u16*)(ws + off); off += (size_t)SH_ * D_ * 2;
  u16* sb_1  = (u16*)(ws + off); off += (size_t)SH_ * D_ * 2;
  u16* sb_2  = (u16*)(ws + off); off += (size_t)D_ * SH_ * 2;
  int*   tok_of = (int*)  (ws + off); off += NTOK * TOPK * 4;
  float* w_of   = (float*)(ws + off); off += NTOK * TOPK * 4;
  float* sg     = (float*)(ws + off); off += NTOK * 4;
  int*   topk_e = (int*)  (ws + off); off += NTOK * TOPK * 4;
  float* topk_w = (float*)(ws + off); off += NTOK * TOPK * 4;
  int*   counts = (int*)  (ws + off); off += 64;
  int*   offs   = (int*)  (ws + off); off += 128;
  int*   fill   = (int*)  (ws + off); off += 64;
  int*   desc_e = (int*)  (ws + off); off += NDESC * 4;
  int*   desc_m = (int*)  (ws + off); off += NDESC * 4;

  hipMemsetAsync(counts, 0, 256, stream);   // counts + offs + fill

  cvt_k<<<dim3(NTOK * D_ / 1024), 256, 0, stream>>>(x, xb);
  cvt_k<<<dim3(E_ * H_ * D_ / 1024), 256, 0, stream>>>(w_gate, wb_g);
  cvt_k<<<dim3(E_ * H_ * D_ / 1024), 256, 0, stream>>>(w1, wb_1);
  cvt_k<<<dim3(E_ * D_ * H_ / 1024), 256, 0, stream>>>(w2, wb_2);
  cvt_k<<<dim3(SH_ * D_ / 1024), 256, 0, stream>>>(sh_wg, sb_g);
  cvt_k<<<dim3(SH_ * D_ / 1024), 256, 0, stream>>>(sh_w1, sb_1);
  cvt_k<<<dim3(D_ * SH_ / 1024), 256, 0, stream>>>(sh_w2, sb_2);

  router_k<<<dim3(NTOK / RTOK), 256, 0, stream>>>(x, gate_w, sh_gw, topk_e, topk_w, sg, counts);
  scan_k<<<dim3(1), 64, 0, stream>>>(counts, offs, desc_e, desc_m);
  scatter_k<<<dim3((NTOK + 255) / 256), 256, 0, stream>>>(topk_e, topk_w, offs, fill, tok_of, w_of);

  // shared expert first: its down-projection STOREs (covers all of out, no memset)
  up_kernel<<<dim3(NTOK/128, SH_/128), 256, 0, stream>>>(
      xb, sb_g, sb_1, h_sh, SH_, nullptr, nullptr, nullptr, nullptr, nullptr);
  down_kernel<<<dim3(NTOK/128, D_/128), 256, 0, stream>>>(
      h_sh, SH_, sb_2, out, nullptr, sg, nullptr, nullptr, nullptr, nullptr, /*atomic=*/0);

  // routed experts via compact chunk-descriptor grid
  up_kernel<<<dim3(NDESC, H_/128), 256, 0, stream>>>(
      xb, wb_g, wb_1, h_exp, H_, tok_of, offs, counts, desc_e, desc_m);
  down_kernel<<<dim3(NDESC, D_/128), 256, 0, stream>>>(
      h_exp, H_, wb_2, out, tok_of, w_of, offs, counts, desc_e, desc_m, /*atomic=*/1);

  (void)in_sizes; (void)n_in; (void)ws_size;
}

// Round 2
// 523.898 us; speedup vs baseline: 1.0641x; 1.0357x over previous
//
#include <hip/hip_runtime.h>
#include <stdint.h>

#define E_    16
#define TOPK  2
#define D_    1024
#define H_    1024
#define SH_   2048
#define NTOK  4096
#define BK    32      // K-step (u16 elements); tile rows are 64B
#define NDESC 80      // max expert chunks: 8192/128 + 16 partials
#define RTOK  16      // router tokens per block

typedef unsigned short u16;
typedef __attribute__((ext_vector_type(8))) __bf16 bf16x8;
typedef __attribute__((ext_vector_type(4))) float  f32x4;

__device__ __forceinline__ u16 f2bf(float f) {
  union { float f; unsigned int u; } v; v.f = f;
  unsigned int u = v.u;
  return (u16)((u + 0x7fffu + ((u >> 16) & 1u)) >> 16);   // RN-even
}

// async global->LDS, 16B per lane. LDS dest is wave-uniform base + lane*16
// (m104); global src is per-lane (m173) so gather is legal.
__device__ __forceinline__ void gload16(const void* g, void* l) {
  __builtin_amdgcn_global_load_lds(
      (const __attribute__((address_space(1))) unsigned int*)g,
      (__attribute__((address_space(3))) unsigned int*)l, 16, 0, 0);
}

// XCD-bijective swizzle (T1, m204-safe since nb%8==0 for all our grids):
// XCD k owns a CONTIGUOUS work range, decomposed x-major / y-fastest so the
// x-tile (A rows) stays L2-resident while the y-streamed weights flow through.
__device__ __forceinline__ void xcd_swz(int gx, int gy, int* ox, int* oy) {
  int nb  = gx * gy;
  int bid = blockIdx.x + gx * blockIdx.y;
  int l   = bid;
  if ((nb & 7) == 0) l = (bid & 7) * (nb >> 3) + (bid >> 3);
  int x = l / gy;
  *ox = x; *oy = l - x * gy;
}

// ---------------- fp32 -> bf16 converter ----------------
__global__ __launch_bounds__(256) void cvt_k(const float* __restrict__ src,
                                             u16* __restrict__ dst) {
  int i = blockIdx.x * 256 + threadIdx.x;      // one float4 per thread
  float4 f = ((const float4*)src)[i];
  ushort4 o; o.x = f2bf(f.x); o.y = f2bf(f.y); o.z = f2bf(f.z); o.w = f2bf(f.w);
  ((ushort4*)dst)[i] = o;
}

// ---------------- router: 16 tokens/block, thread=(expert,token), fp32 ------
__global__ __launch_bounds__(256) void router_k(
    const float* __restrict__ x, const float* __restrict__ gate_w,
    const float* __restrict__ shared_gate_w,
    int* __restrict__ topk_e, float* __restrict__ topk_w,
    float* __restrict__ sg, int* __restrict__ counts) {
  __shared__ float xs[RTOK][132];   // +4 pad: rows offset by 4 banks
  __shared__ float lg[RTOK][16];
  __shared__ float sgp[RTOK][16];

  int tid = threadIdx.x;
  int e   = tid >> 4;               // 0..15
  int tt  = tid & 15;               // 0..15
  int t0  = blockIdx.x * RTOK;

  float acc = 0.f, sga = 0.f;
  for (int c = 0; c < D_; c += 128) {
    __syncthreads();                // xs reuse from previous chunk done
    #pragma unroll
    for (int i = 0; i < 2; i++) {
      int f = i * 256 + tid;        // 0..511 float4 units, fully coalesced
      int r = f >> 5, c4 = f & 31;
      *(float4*)&xs[r][c4 * 4] =
          *(const float4*)&x[(size_t)(t0 + r) * D_ + c + c4 * 4];
    }
    __syncthreads();
    const float* gw = &gate_w[(size_t)e * D_ + c];
    #pragma unroll
    for (int d4 = 0; d4 < 32; d4++) {
      float4 g  = *(const float4*)&gw[d4 * 4];
      float4 xv = *(const float4*)&xs[tt][d4 * 4];
      acc += xv.x * g.x + xv.y * g.y + xv.z * g.z + xv.w * g.w;
    }
    // shared-gate partial: this thread covers d in [e*8, e*8+8)
    #pragma unroll
    for (int j = 0; j < 8; j += 4) {
      float4 s  = *(const float4*)&shared_gate_w[c + e * 8 + j];
      float4 xv = *(const float4*)&xs[tt][e * 8 + j];
      sga += xv.x * s.x + xv.y * s.y + xv.z * s.z + xv.w * s.w;
    }
  }
  lg[tt][e]  = acc;
  sgp[tt][e] = sga;
  __syncthreads();

  if (tid < RTOK) {
    int t = t0 + tid;
    float l[16];
    #pragma unroll
    for (int k = 0; k < 16; k++) l[k] = lg[tid][k];
    int i0 = 0; float l0 = l[0];
    for (int k = 1; k < 16; k++) if (l[k] > l0) { l0 = l[k]; i0 = k; }
    int i1 = -1; float l1 = -3.4e38f;
    for (int k = 0; k < 16; k++) if (k != i0 && l[k] > l1) { l1 = l[k]; i1 = k; }
    float w0 = 1.f / (1.f + expf(l1 - l0));   // == p0/(p0+p1)
    float s = 0.f;
    #pragma unroll
    for (int k = 0; k < 16; k++) s += sgp[tid][k];
    topk_e[2*t] = i0; topk_e[2*t+1] = i1;
    topk_w[2*t] = w0; topk_w[2*t+1] = 1.f - w0;
    sg[t] = 1.f / (1.f + expf(-s));
    atomicAdd(&counts[i0], 1);
    atomicAdd(&counts[i1], 1);
  }
}

// prefix scan + compact chunk-descriptor table (chunk -> expert, m0)
__global__ void scan_k(const int* __restrict__ counts, int* __restrict__ offs,
                       int* __restrict__ desc_e, int* __restrict__ desc_m) {
  if (threadIdx.x == 0) {
    int s = 0, n = 0;
    for (int e = 0; e < E_; e++) {
      offs[e] = s;
      for (int m0 = 0; m0 < counts[e]; m0 += 128) {
        desc_e[n] = e; desc_m[n] = m0; n++;
      }
      s += counts[e];
    }
    offs[E_] = s;
    for (; n < NDESC; n++) { desc_e[n] = -1; desc_m[n] = 0; }
  }
}

__global__ __launch_bounds__(256) void scatter_k(
    const int* __restrict__ topk_e, const float* __restrict__ topk_w,
    const int* __restrict__ offs, int* __restrict__ fill,
    int* __restrict__ tok_of, float* __restrict__ w_of) {
  int t = blockIdx.x * 256 + threadIdx.x;
  if (t >= NTOK) return;
  for (int k = 0; k < TOPK; k++) {
    int e = topk_e[2*t+k];
    int p = atomicAdd(&fill[e], 1);
    int slot = offs[e] + p;
    tok_of[slot] = t;
    w_of[slot]   = topk_w[2*t+k];
  }
}

// ---------------- fused gated up-projection: h = (x@W1^T) * silu(x@Wg^T) ----
// Counted-vmcnt pipeline (T4): depth-2 prefetch, raw s_barrier, main loop
// waits vmcnt(6) (prev tile only) -- never drains to 0 except the peel tail.
__global__ __launch_bounds__(256, 2) void up_kernel(
    const u16* __restrict__ Xb,
    const u16* __restrict__ Wg_all, const u16* __restrict__ W1_all,
    u16* __restrict__ Hout, int H,
    const int* __restrict__ tok_of,
    const int* __restrict__ offs, const int* __restrict__ counts,
    const int* __restrict__ desc_e, const int* __restrict__ desc_m) {
  int bx, by;
  xcd_swz(gridDim.x, gridDim.y, &bx, &by);

  int e, m0, cnt, pbase;
  if (desc_e) {
    e = desc_e[bx];
    if (e < 0) return;
    m0 = desc_m[bx];
    cnt = counts[e]; pbase = offs[e];
  } else {
    e = 0; m0 = bx * 128; cnt = NTOK; pbase = 0;
  }
  int n0 = by * 128;
  const u16* Wg = Wg_all + (size_t)e * H * D_;
  const u16* W1 = W1_all + (size_t)e * H * D_;

  __shared__ u16 smem[2 * 3 * 4096];   // [buf][A,G,U][128*BK]  48KB

  int tid  = threadIdx.x;
  int lane = tid & 63, wave = tid >> 6;
  int wm = wave & 1, wn = wave >> 1;
  int l16 = lane & 15, quad = lane >> 4;

  // staging: wave w owns rows [w*16, w*16+16) (+64 for 2nd issue); lane l
  // lands at wave_base + l*16 bytes = row w*16 + l/4, col (l&3)*8 elems.
  int sr = wave * 16 + (lane >> 2);
  int sc = (lane & 3) * 8;

  int gm0 = m0 + sr;      if (gm0 >= cnt) gm0 = cnt - 1;
  int gm1 = m0 + sr + 64; if (gm1 >= cnt) gm1 = cnt - 1;
  int tok0 = tok_of ? tok_of[pbase + gm0] : gm0;
  int tok1 = tok_of ? tok_of[pbase + gm1] : gm1;
  const u16* pa0 = Xb + (size_t)tok0 * D_ + sc;
  const u16* pa1 = Xb + (size_t)tok1 * D_ + sc;
  const u16* pg0 = Wg + (size_t)(n0 + sr) * D_ + sc;
  const u16* pg1 = pg0 + (size_t)64 * D_;
  const u16* pu0 = W1 + (size_t)(n0 + sr) * D_ + sc;
  const u16* pu1 = pu0 + (size_t)64 * D_;

  int lbase = wave * 512;   // u16 units: wave*1024B within a tile

  f32x4 accg[4][4], accu[4][4];
  f32x4 zero = {0.f, 0.f, 0.f, 0.f};
  #pragma unroll
  for (int i = 0; i < 4; i++)
    #pragma unroll
    for (int j = 0; j < 4; j++) { accg[i][j] = zero; accu[i][j] = zero; }

#define STAGE_UP(b) do {                                            \
    u16* s_ = smem + (b) * 12288 + lbase;                           \
    gload16(pa0, s_);        gload16(pa1, s_ + 2048);               \
    gload16(pg0, s_ + 4096); gload16(pg1, s_ + 6144);               \
    gload16(pu0, s_ + 8192); gload16(pu1, s_ + 10240);              \
    pa0 += BK; pa1 += BK; pg0 += BK; pg1 += BK; pu0 += BK; pu1 += BK; \
  } while (0)

  STAGE_UP(0);                      // tile 0   (6 loads in flight)
  STAGE_UP(1);                      // tile 1   (12 in flight)
  int buf = 0;
  const int nt = D_ / BK;           // 32

  for (int t = 0; t < nt; ++t) {
    if (t + 1 < nt) asm volatile("s_waitcnt vmcnt(6)" ::: "memory");
    else            asm volatile("s_waitcnt vmcnt(0)" ::: "memory");
    __builtin_amdgcn_s_barrier();          // tile t complete in LDS, all waves
    __builtin_amdgcn_sched_barrier(0);     // rule #18: no hoist above barrier

    const u16* base = smem + buf * 12288;
    bf16x8 af[4], gf[4], uf[4];
    #pragma unroll
    for (int i = 0; i < 4; i++) {
      af[i] = *(const bf16x8*)&base[(wm*64 + i*16 + l16)*BK + quad*8];
      gf[i] = *(const bf16x8*)&base[4096 + (wn*64 + i*16 + l16)*BK + quad*8];
      uf[i] = *(const bf16x8*)&base[8192 + (wn*64 + i*16 + l16)*BK + quad*8];
    }
    #pragma unroll
    for (int i = 0; i < 4; i++)
      #pragma unroll
      for (int j = 0; j < 4; j++) {
        accg[i][j] = __builtin_amdgcn_mfma_f32_16x16x32_bf16(af[i], gf[j], accg[i][j], 0, 0, 0);
        accu[i][j] = __builtin_amdgcn_mfma_f32_16x16x32_bf16(af[i], uf[j], accu[i][j], 0, 0, 0);
      }

    __builtin_amdgcn_sched_barrier(0);     // reads stay above barrier #2
    __builtin_amdgcn_s_barrier();          // all waves done reading buf
    if (t + 2 < nt) STAGE_UP(buf);         // tile t+2 -> just-freed buffer
    buf ^= 1;
  }
#undef STAGE_UP

  // epilogue: h = u * silu(g)  (C/D map: col=lane&15, row=quad*4+reg — verified)
  #pragma unroll
  for (int i = 0; i < 4; i++) {
    #pragma unroll
    for (int r = 0; r < 4; r++) {
      int m = m0 + wm*64 + i*16 + quad*4 + r;
      if (m < cnt) {
        size_t prow = (size_t)(pbase + m) * H;
        #pragma unroll
        for (int j = 0; j < 4; j++) {
          int n = n0 + wn*64 + j*16 + l16;
          float g = accg[i][j][r];
          float u = accu[i][j][r];
          Hout[prow + n] = f2bf(u * (g / (1.f + expf(-g))));
        }
      }
    }
  }
}

// ---------------- down-projection: out[tok] (+)= scale * (h @ W2^T) ---------
__global__ __launch_bounds__(256, 3) void down_kernel(
    const u16* __restrict__ Hbuf, int K,
    const u16* __restrict__ W2_all,
    float* __restrict__ out,
    const int* __restrict__ tok_of, const float* __restrict__ scale,
    const int* __restrict__ offs, const int* __restrict__ counts,
    const int* __restrict__ desc_e, const int* __restrict__ desc_m,
    int atomic_mode) {
  int bx, by;
  xcd_swz(gridDim.x, gridDim.y, &bx, &by);

  int e, m0, cnt, pbase;
  if (desc_e) {
    e = desc_e[bx];
    if (e < 0) return;
    m0 = desc_m[bx];
    cnt = counts[e]; pbase = offs[e];
  } else {
    e = 0; m0 = bx * 128; cnt = NTOK; pbase = 0;
  }
  int n0 = by * 128;
  const u16* W2 = W2_all + (size_t)e * D_ * K;

  __shared__ u16 smem[2 * 2 * 4096];   // [buf][A,B][128*BK]  32KB

  int tid  = threadIdx.x;
  int lane = tid & 63, wave = tid >> 6;
  int wm = wave & 1, wn = wave >> 1;
  int l16 = lane & 15, quad = lane >> 4;

  int sr = wave * 16 + (lane >> 2);
  int sc = (lane & 3) * 8;

  int gm0 = m0 + sr;      if (gm0 >= cnt) gm0 = cnt - 1;
  int gm1 = m0 + sr + 64; if (gm1 >= cnt) gm1 = cnt - 1;
  const u16* pa0 = Hbuf + (size_t)(pbase + gm0) * K + sc;
  const u16* pa1 = Hbuf + (size_t)(pbase + gm1) * K + sc;
  const u16* pb0 = W2 + (size_t)(n0 + sr) * K + sc;
  const u16* pb1 = pb0 + (size_t)64 * K;

  int lbase = wave * 512;

  f32x4 acc[4][4];
  f32x4 zero = {0.f, 0.f, 0.f, 0.f};
  #pragma unroll
  for (int i = 0; i < 4; i++)
    #pragma unroll
    for (int j = 0; j < 4; j++) acc[i][j] = zero;

#define STAGE_DN(b) do {                                \
    u16* s_ = smem + (b) * 8192 + lbase;                \
    gload16(pa0, s_);        gload16(pa1, s_ + 2048);   \
    gload16(pb0, s_ + 4096); gload16(pb1, s_ + 6144);   \
    pa0 += BK; pa1 += BK; pb0 += BK; pb1 += BK;         \
  } while (0)

  STAGE_DN(0);                      // tile 0
  STAGE_DN(1);                      // tile 1
  int buf = 0;
  const int nt = K / BK;

  for (int t = 0; t < nt; ++t) {
    if (t + 1 < nt) asm volatile("s_waitcnt vmcnt(4)" ::: "memory");
    else            asm volatile("s_waitcnt vmcnt(0)" ::: "memory");
    __builtin_amdgcn_s_barrier();
    __builtin_amdgcn_sched_barrier(0);

    const u16* base = smem + buf * 8192;
    bf16x8 af[4], bfr[4];
    #pragma unroll
    for (int i = 0; i < 4; i++) {
      af[i]  = *(const bf16x8*)&base[(wm*64 + i*16 + l16)*BK + quad*8];
      bfr[i] = *(const bf16x8*)&base[4096 + (wn*64 + i*16 + l16)*BK + quad*8];
    }
    #pragma unroll
    for (int i = 0; i < 4; i++)
      #pragma unroll
      for (int j = 0; j < 4; j++)
        acc[i][j] = __builtin_amdgcn_mfma_f32_16x16x32_bf16(af[i], bfr[j], acc[i][j], 0, 0, 0);

    __builtin_amdgcn_sched_barrier(0);
    __builtin_amdgcn_s_barrier();
    if (t + 2 < nt) STAGE_DN(buf);
    buf ^= 1;
  }
#undef STAGE_DN

  #pragma unroll
  for (int i = 0; i < 4; i++) {
    #pragma unroll
    for (int r = 0; r < 4; r++) {
      int m = m0 + wm*64 + i*16 + quad*4 + r;
      if (m < cnt) {
        int p   = pbase + m;
        int tok = tok_of ? tok_of[p] : p;
        float sc2 = scale[p];
        if (atomic_mode) {
          #pragma unroll
          for (int j = 0; j < 4; j++) {
            int n = n0 + wn*64 + j*16 + l16;
            atomicAdd(&out[(size_t)tok * D_ + n], sc2 * acc[i][j][r]);
          }
        } else {
          #pragma unroll
          for (int j = 0; j < 4; j++) {
            int n = n0 + wn*64 + j*16 + l16;
            out[(size_t)tok * D_ + n] = sc2 * acc[i][j][r];
          }
        }
      }
    }
  }
}

extern "C" void kernel_launch(void* const* d_in, const int* in_sizes, int n_in,
                              void* d_out, int out_size, void* d_ws, size_t ws_size,
                              hipStream_t stream) {
  const float* x      = (const float*)d_in[0];
  const float* gate_w = (const float*)d_in[1];
  const float* w_gate = (const float*)d_in[2];
  const float* w1     = (const float*)d_in[3];
  const float* w2     = (const float*)d_in[4];
  const float* sh_wg  = (const float*)d_in[5];
  const float* sh_w1  = (const float*)d_in[6];
  const float* sh_w2  = (const float*)d_in[7];
  const float* sh_gw  = (const float*)d_in[8];
  float* out = (float*)d_out;

  char* ws = (char*)d_ws;
  size_t off = 0;
  u16* xb    = (u16*)(ws + off); off += (size_t)NTOK * D_ * 2;
  u16* h_exp = (u16*)(ws + off); off += (size_t)NTOK * TOPK * H_ * 2;
  u16* h_sh  = (u16*)(ws + off); off += (size_t)NTOK * SH_ * 2;
  u16* wb_g  = (u16*)(ws + off); off += (size_t)E_ * H_ * D_ * 2;
  u16* wb_1  = (u16*)(ws + off); off += (size_t)E_ * H_ * D_ * 2;
  u16* wb_2  = (u16*)(ws + off); off += (size_t)E_ * D_ * H_ * 2;
  u16* sb_g  = (u16*)(ws + off); off += (size_t)SH_ * D_ * 2;
  u16* sb_1  = (u16*)(ws + off); off += (size_t)SH_ * D_ * 2;
  u16* sb_2  = (u16*)(ws + off); off += (size_t)D_ * SH_ * 2;
  int*   tok_of = (int*)  (ws + off); off += NTOK * TOPK * 4;
  float* w_of   = (float*)(ws + off); off += NTOK * TOPK * 4;
  float* sg     = (float*)(ws + off); off += NTOK * 4;
  int*   topk_e = (int*)  (ws + off); off += NTOK * TOPK * 4;
  float* topk_w = (float*)(ws + off); off += NTOK * TOPK * 4;
  int*   counts = (int*)  (ws + off); off += 64;
  int*   offs   = (int*)  (ws + off); off += 128;
  int*   fill   = (int*)  (ws + off); off += 64;
  int*   desc_e = (int*)  (ws + off); off += NDESC * 4;
  int*   desc_m = (int*)  (ws + off); off += NDESC * 4;

  hipMemsetAsync(counts, 0, 256, stream);   // counts + offs + fill

  cvt_k<<<dim3(NTOK * D_ / 1024), 256, 0, stream>>>(x, xb);
  cvt_k<<<dim3(E_ * H_ * D_ / 1024), 256, 0, stream>>>(w_gate, wb_g);
  cvt_k<<<dim3(E_ * H_ * D_ / 1024), 256, 0, stream>>>(w1, wb_1);
  cvt_k<<<dim3(E_ * D_ * H_ / 1024), 256, 0, stream>>>(w2, wb_2);
  cvt_k<<<dim3(SH_ * D_ / 1024), 256, 0, stream>>>(sh_wg, sb_g);
  cvt_k<<<dim3(SH_ * D_ / 1024), 256, 0, stream>>>(sh_w1, sb_1);
  cvt_k<<<dim3(D_ * SH_ / 1024), 256, 0, stream>>>(sh_w2, sb_2);

  router_k<<<dim3(NTOK / RTOK), 256, 0, stream>>>(x, gate_w, sh_gw, topk_e, topk_w, sg, counts);
  scan_k<<<dim3(1), 64, 0, stream>>>(counts, offs, desc_e, desc_m);
  scatter_k<<<dim3((NTOK + 255) / 256), 256, 0, stream>>>(topk_e, topk_w, offs, fill, tok_of, w_of);

  // shared expert first: its down-projection STOREs (covers all of out, no memset)
  up_kernel<<<dim3(NTOK/128, SH_/128), 256, 0, stream>>>(
      xb, sb_g, sb_1, h_sh, SH_, nullptr, nullptr, nullptr, nullptr, nullptr);
  down_kernel<<<dim3(NTOK/128, D_/128), 256, 0, stream>>>(
      h_sh, SH_, sb_2, out, nullptr, sg, nullptr, nullptr, nullptr, nullptr, /*atomic=*/0);

  // routed experts via compact chunk-descriptor grid
  up_kernel<<<dim3(NDESC, H_/128), 256, 0, stream>>>(
      xb, wb_g, wb_1, h_exp, H_, tok_of, offs, counts, desc_e, desc_m);
  down_kernel<<<dim3(NDESC, D_/128), 256, 0, stream>>>(
      h_exp, H_, wb_2, out, tok_of, w_of, offs, counts, desc_e, desc_m, /*atomic=*/1);

  (void)in_sizes; (void)n_in; (void)ws_size;
}

// Round 3
// 464.558 us; speedup vs baseline: 1.2000x; 1.1277x over previous
//
#include <hip/hip_runtime.h>
#include <stdint.h>

#define E_    16
#define TOPK  2
#define D_    1024
#define H_    1024
#define SH_   2048
#define NTOK  4096
#define BK    32      // K-step (u16 elements); tile rows are 64B
#define NDESC 80      // max expert chunks: 8192/128 + 16 partials
#define RTOK  16      // router tokens per block
#define NRBLK (NTOK / RTOK)       // 256 router blocks
#define NSHUP (NTOK/128 * SH_/128)  // 512 shared-up blocks (gy=16)
#define NRTUP (NDESC * H_/128)      // 640 routed-up blocks (gy=8)
#define NSHDN (NTOK/128 * D_/128)   // 256 shared-down blocks (gy=8)
#define NRTDN (NDESC * D_/128)      // 640 routed-down blocks (gy=8)

typedef unsigned short u16;
typedef __attribute__((ext_vector_type(8))) __bf16 bf16x8;
typedef __attribute__((ext_vector_type(4))) float  f32x4;

struct CvtTable {
  const float* src[7];
  u16*         dst[7];
  int          start[8];   // block-range prefix over cvt blocks
};

__device__ __forceinline__ u16 f2bf(float f) {
  union { float f; unsigned int u; } v; v.f = f;
  unsigned int u = v.u;
  return (u16)((u + 0x7fffu + ((u >> 16) & 1u)) >> 16);   // RN-even
}

// async global->LDS, 16B per lane. LDS dest is wave-uniform base + lane*16
// (m104); global src is per-lane (m173) so gather is legal.
__device__ __forceinline__ void gload16(const void* g, void* l) {
  __builtin_amdgcn_global_load_lds(
      (const __attribute__((address_space(1))) unsigned int*)g,
      (__attribute__((address_space(3))) unsigned int*)l, 16, 0, 0);
}

// XCD-bijective swizzle over a 1D role range (nb % 8 == 0 for all our roles):
// XCD k owns a contiguous chunk of the role's linear block space.
__device__ __forceinline__ int swz8(int b, int nb) {
  return (b & 7) * (nb >> 3) + (b >> 3);
}

// ---------------- mega kernel 1: router blocks + all fp32->bf16 cvt --------
__global__ __launch_bounds__(256) void cvtrouter_k(
    CvtTable ct,
    const float* __restrict__ x, const float* __restrict__ gate_w,
    const float* __restrict__ shared_gate_w,
    int* __restrict__ topk_e, float* __restrict__ topk_w,
    float* __restrict__ sg, int* __restrict__ counts) {
  __shared__ float xs[RTOK][132];   // +4 pad: rows offset by 4 banks
  __shared__ float lg[RTOK][16];
  __shared__ float sgp[RTOK][16];

  int b   = blockIdx.x;
  int tid = threadIdx.x;

  if (b >= NRBLK) {
    // ---- cvt role: segmented streaming convert, one float4 per thread ----
    int cb = b - NRBLK;
    int s = 0;
    while (cb >= ct.start[s + 1]) s++;       // <=7 uniform iterations
    int i = (cb - ct.start[s]) * 256 + tid;
    float4 f = ((const float4*)ct.src[s])[i];
    ushort4 o; o.x = f2bf(f.x); o.y = f2bf(f.y); o.z = f2bf(f.z); o.w = f2bf(f.w);
    ((ushort4*)ct.dst[s])[i] = o;
    return;
  }

  // ---- router role: 16 tokens/block, thread=(expert,token), fp32 ----
  int e   = tid >> 4;               // 0..15
  int tt  = tid & 15;               // 0..15
  int t0  = b * RTOK;

  float acc = 0.f, sga = 0.f;
  for (int c = 0; c < D_; c += 128) {
    __syncthreads();                // xs reuse from previous chunk done
    #pragma unroll
    for (int i = 0; i < 2; i++) {
      int f = i * 256 + tid;        // 0..511 float4 units, fully coalesced
      int r = f >> 5, c4 = f & 31;
      *(float4*)&xs[r][c4 * 4] =
          *(const float4*)&x[(size_t)(t0 + r) * D_ + c + c4 * 4];
    }
    __syncthreads();
    const float* gw = &gate_w[(size_t)e * D_ + c];
    #pragma unroll
    for (int d4 = 0; d4 < 32; d4++) {
      float4 g  = *(const float4*)&gw[d4 * 4];
      float4 xv = *(const float4*)&xs[tt][d4 * 4];
      acc += xv.x * g.x + xv.y * g.y + xv.z * g.z + xv.w * g.w;
    }
    // shared-gate partial: this thread covers d in [e*8, e*8+8)
    #pragma unroll
    for (int j = 0; j < 8; j += 4) {
      float4 s2 = *(const float4*)&shared_gate_w[c + e * 8 + j];
      float4 xv = *(const float4*)&xs[tt][e * 8 + j];
      sga += xv.x * s2.x + xv.y * s2.y + xv.z * s2.z + xv.w * s2.w;
    }
  }
  lg[tt][e]  = acc;
  sgp[tt][e] = sga;
  __syncthreads();

  if (tid < RTOK) {
    int t = t0 + tid;
    float l[16];
    #pragma unroll
    for (int k = 0; k < 16; k++) l[k] = lg[tid][k];
    int i0 = 0; float l0 = l[0];
    for (int k = 1; k < 16; k++) if (l[k] > l0) { l0 = l[k]; i0 = k; }
    int i1 = -1; float l1 = -3.4e38f;
    for (int k = 0; k < 16; k++) if (k != i0 && l[k] > l1) { l1 = l[k]; i1 = k; }
    float w0 = 1.f / (1.f + expf(l1 - l0));   // == p0/(p0+p1)
    float s = 0.f;
    #pragma unroll
    for (int k = 0; k < 16; k++) s += sgp[tid][k];
    topk_e[2*t] = i0; topk_e[2*t+1] = i1;
    topk_w[2*t] = w0; topk_w[2*t+1] = 1.f - w0;
    sg[t] = 1.f / (1.f + expf(-s));
    atomicAdd(&counts[i0], 1);
    atomicAdd(&counts[i1], 1);
  }
}

// ---------------- scan (1 thread) + scatter (256 threads), one block -------
__global__ __launch_bounds__(256) void scan_scatter_k(
    const int* __restrict__ counts, int* __restrict__ offs,
    int* __restrict__ desc_e, int* __restrict__ desc_m,
    const int* __restrict__ topk_e, const float* __restrict__ topk_w,
    int* __restrict__ fill, int* __restrict__ tok_of, float* __restrict__ w_of) {
  if (threadIdx.x == 0) {
    int s = 0, n = 0;
    for (int e = 0; e < E_; e++) {
      offs[e] = s;
      for (int m0 = 0; m0 < counts[e]; m0 += 128) {
        desc_e[n] = e; desc_m[n] = m0; n++;
      }
      s += counts[e];
    }
    offs[E_] = s;
    for (; n < NDESC; n++) { desc_e[n] = -1; desc_m[n] = 0; }
  }
  __syncthreads();
  for (int t = threadIdx.x; t < NTOK; t += 256) {
    for (int k = 0; k < TOPK; k++) {
      int e = topk_e[2*t+k];
      int p = atomicAdd(&fill[e], 1);
      int slot = offs[e] + p;
      tok_of[slot] = t;
      w_of[slot]   = topk_w[2*t+k];
    }
  }
}

// ---------------- merged up-projection: shared + routed in one grid --------
// h = (x@W1^T) * silu(x@Wg^T). Counted-vmcnt depth-2 pipeline (T4).
// Both roles have K = D_ = 1024, identical inner loop -> role picked per block.
__global__ __launch_bounds__(256, 2) void up_merged(
    const u16* __restrict__ Xb,
    const u16* __restrict__ sWg, const u16* __restrict__ sW1, u16* __restrict__ sHout,
    const u16* __restrict__ rWg_all, const u16* __restrict__ rW1_all, u16* __restrict__ rHout,
    const int* __restrict__ tok_of,
    const int* __restrict__ offs, const int* __restrict__ counts,
    const int* __restrict__ desc_e, const int* __restrict__ desc_m) {
  int bid = blockIdx.x;
  const u16 *Wg, *W1; u16* Hout; int Hdim;
  int m0, cnt, pbase, n0;
  const int* tof;
  if (bid < NSHUP) {                        // shared-expert role (gy = 16)
    int l = swz8(bid, NSHUP);
    int bx = l >> 4, by = l & 15;
    m0 = bx * 128; cnt = NTOK; pbase = 0; tof = nullptr;
    Wg = sWg; W1 = sW1; Hout = sHout; Hdim = SH_;
    n0 = by * 128;
  } else {                                  // routed role (gy = 8)
    int r = bid - NSHUP;
    int l = swz8(r, NRTUP);
    int bx = l >> 3, by = l & 7;
    int e = desc_e[bx];
    if (e < 0) return;
    m0 = desc_m[bx]; cnt = counts[e]; pbase = offs[e]; tof = tok_of;
    Wg = rWg_all + (size_t)e * H_ * D_;
    W1 = rW1_all + (size_t)e * H_ * D_;
    Hout = rHout; Hdim = H_;
    n0 = by * 128;
  }

  __shared__ u16 smem[2 * 3 * 4096];   // [buf][A,G,U][128*BK]  48KB

  int tid  = threadIdx.x;
  int lane = tid & 63, wave = tid >> 6;
  int wm = wave & 1, wn = wave >> 1;
  int l16 = lane & 15, quad = lane >> 4;

  // staging: wave w owns rows [w*16, w*16+16) (+64 for 2nd issue); lane l
  // lands at wave_base + l*16 bytes = row w*16 + l/4, col (l&3)*8 elems.
  int sr = wave * 16 + (lane >> 2);
  int sc = (lane & 3) * 8;

  int gm0 = m0 + sr;      if (gm0 >= cnt) gm0 = cnt - 1;
  int gm1 = m0 + sr + 64; if (gm1 >= cnt) gm1 = cnt - 1;
  int tok0 = tof ? tof[pbase + gm0] : gm0;
  int tok1 = tof ? tof[pbase + gm1] : gm1;
  const u16* pa0 = Xb + (size_t)tok0 * D_ + sc;
  const u16* pa1 = Xb + (size_t)tok1 * D_ + sc;
  const u16* pg0 = Wg + (size_t)(n0 + sr) * D_ + sc;
  const u16* pg1 = pg0 + (size_t)64 * D_;
  const u16* pu0 = W1 + (size_t)(n0 + sr) * D_ + sc;
  const u16* pu1 = pu0 + (size_t)64 * D_;

  int lbase = wave * 512;   // u16 units: wave*1024B within a tile

  f32x4 accg[4][4], accu[4][4];
  f32x4 zero = {0.f, 0.f, 0.f, 0.f};
  #pragma unroll
  for (int i = 0; i < 4; i++)
    #pragma unroll
    for (int j = 0; j < 4; j++) { accg[i][j] = zero; accu[i][j] = zero; }

#define STAGE_UP(b) do {                                            \
    u16* s_ = smem + (b) * 12288 + lbase;                           \
    gload16(pa0, s_);        gload16(pa1, s_ + 2048);               \
    gload16(pg0, s_ + 4096); gload16(pg1, s_ + 6144);               \
    gload16(pu0, s_ + 8192); gload16(pu1, s_ + 10240);              \
    pa0 += BK; pa1 += BK; pg0 += BK; pg1 += BK; pu0 += BK; pu1 += BK; \
  } while (0)

  STAGE_UP(0);                      // tile 0   (6 loads in flight)
  STAGE_UP(1);                      // tile 1   (12 in flight)
  int buf = 0;
  const int nt = D_ / BK;           // 32

  for (int t = 0; t < nt; ++t) {
    if (t + 1 < nt) asm volatile("s_waitcnt vmcnt(6)" ::: "memory");
    else            asm volatile("s_waitcnt vmcnt(0)" ::: "memory");
    __builtin_amdgcn_s_barrier();          // tile t complete in LDS, all waves
    __builtin_amdgcn_sched_barrier(0);     // rule #18: no hoist above barrier

    const u16* base = smem + buf * 12288;
    bf16x8 af[4], gf[4], uf[4];
    #pragma unroll
    for (int i = 0; i < 4; i++) {
      af[i] = *(const bf16x8*)&base[(wm*64 + i*16 + l16)*BK + quad*8];
      gf[i] = *(const bf16x8*)&base[4096 + (wn*64 + i*16 + l16)*BK + quad*8];
      uf[i] = *(const bf16x8*)&base[8192 + (wn*64 + i*16 + l16)*BK + quad*8];
    }
    #pragma unroll
    for (int i = 0; i < 4; i++)
      #pragma unroll
      for (int j = 0; j < 4; j++) {
        accg[i][j] = __builtin_amdgcn_mfma_f32_16x16x32_bf16(af[i], gf[j], accg[i][j], 0, 0, 0);
        accu[i][j] = __builtin_amdgcn_mfma_f32_16x16x32_bf16(af[i], uf[j], accu[i][j], 0, 0, 0);
      }

    __builtin_amdgcn_sched_barrier(0);     // reads stay above barrier #2
    __builtin_amdgcn_s_barrier();          // all waves done reading buf
    if (t + 2 < nt) STAGE_UP(buf);         // tile t+2 -> just-freed buffer
    buf ^= 1;
  }
#undef STAGE_UP

  // epilogue: h = u * silu(g)  (C/D map: col=lane&15, row=quad*4+reg — verified)
  #pragma unroll
  for (int i = 0; i < 4; i++) {
    #pragma unroll
    for (int r = 0; r < 4; r++) {
      int m = m0 + wm*64 + i*16 + quad*4 + r;
      if (m < cnt) {
        size_t prow = (size_t)(pbase + m) * Hdim;
        #pragma unroll
        for (int j = 0; j < 4; j++) {
          int n = n0 + wn*64 + j*16 + l16;
          float g = accg[i][j][r];
          float u = accu[i][j][r];
          Hout[prow + n] = f2bf(u * (g / (1.f + expf(-g))));
        }
      }
    }
  }
}

// ---------------- merged down-projection: shared + routed, both atomic -----
// out[tok] += scale * (h @ W2^T); out pre-zeroed by memset.
__global__ __launch_bounds__(256, 3) void down_merged(
    const u16* __restrict__ sHbuf, const u16* __restrict__ sW2, const float* __restrict__ sg,
    const u16* __restrict__ rHbuf, const u16* __restrict__ rW2_all, const float* __restrict__ w_of,
    float* __restrict__ out,
    const int* __restrict__ tok_of,
    const int* __restrict__ offs, const int* __restrict__ counts,
    const int* __restrict__ desc_e, const int* __restrict__ desc_m) {
  int bid = blockIdx.x;
  const u16 *Hbuf, *W2; const float* scale;
  int m0, cnt, pbase, n0, K;
  const int* tof;
  if (bid < NSHDN) {                        // shared role: K = SH_ (gy = 8)
    int l = swz8(bid, NSHDN);
    int bx = l >> 3, by = l & 7;
    m0 = bx * 128; cnt = NTOK; pbase = 0; tof = nullptr;
    Hbuf = sHbuf; W2 = sW2; scale = sg; K = SH_;
    n0 = by * 128;
  } else {                                  // routed role: K = H_ (gy = 8)
    int r = bid - NSHDN;
    int l = swz8(r, NRTDN);
    int bx = l >> 3, by = l & 7;
    int e = desc_e[bx];
    if (e < 0) return;
    m0 = desc_m[bx]; cnt = counts[e]; pbase = offs[e]; tof = tok_of;
    Hbuf = rHbuf; W2 = rW2_all + (size_t)e * D_ * H_; scale = w_of; K = H_;
    n0 = by * 128;
  }

  __shared__ u16 smem[2 * 2 * 4096];   // [buf][A,B][128*BK]  32KB

  int tid  = threadIdx.x;
  int lane = tid & 63, wave = tid >> 6;
  int wm = wave & 1, wn = wave >> 1;
  int l16 = lane & 15, quad = lane >> 4;

  int sr = wave * 16 + (lane >> 2);
  int sc = (lane & 3) * 8;

  int gm0 = m0 + sr;      if (gm0 >= cnt) gm0 = cnt - 1;
  int gm1 = m0 + sr + 64; if (gm1 >= cnt) gm1 = cnt - 1;
  const u16* pa0 = Hbuf + (size_t)(pbase + gm0) * K + sc;
  const u16* pa1 = Hbuf + (size_t)(pbase + gm1) * K + sc;
  const u16* pb0 = W2 + (size_t)(n0 + sr) * K + sc;
  const u16* pb1 = pb0 + (size_t)64 * K;

  int lbase = wave * 512;

  f32x4 acc[4][4];
  f32x4 zero = {0.f, 0.f, 0.f, 0.f};
  #pragma unroll
  for (int i = 0; i < 4; i++)
    #pragma unroll
    for (int j = 0; j < 4; j++) acc[i][j] = zero;

#define STAGE_DN(b) do {                                \
    u16* s_ = smem + (b) * 8192 + lbase;                \
    gload16(pa0, s_);        gload16(pa1, s_ + 2048);   \
    gload16(pb0, s_ + 4096); gload16(pb1, s_ + 6144);   \
    pa0 += BK; pa1 += BK; pb0 += BK; pb1 += BK;         \
  } while (0)

  STAGE_DN(0);                      // tile 0
  STAGE_DN(1);                      // tile 1
  int buf = 0;
  const int nt = K / BK;

  for (int t = 0; t < nt; ++t) {
    if (t + 1 < nt) asm volatile("s_waitcnt vmcnt(4)" ::: "memory");
    else            asm volatile("s_waitcnt vmcnt(0)" ::: "memory");
    __builtin_amdgcn_s_barrier();
    __builtin_amdgcn_sched_barrier(0);

    const u16* base = smem + buf * 8192;
    bf16x8 af[4], bfr[4];
    #pragma unroll
    for (int i = 0; i < 4; i++) {
      af[i]  = *(const bf16x8*)&base[(wm*64 + i*16 + l16)*BK + quad*8];
      bfr[i] = *(const bf16x8*)&base[4096 + (wn*64 + i*16 + l16)*BK + quad*8];
    }
    #pragma unroll
    for (int i = 0; i < 4; i++)
      #pragma unroll
      for (int j = 0; j < 4; j++)
        acc[i][j] = __builtin_amdgcn_mfma_f32_16x16x32_bf16(af[i], bfr[j], acc[i][j], 0, 0, 0);

    __builtin_amdgcn_sched_barrier(0);
    __builtin_amdgcn_s_barrier();
    if (t + 2 < nt) STAGE_DN(buf);
    buf ^= 1;
  }
#undef STAGE_DN

  #pragma unroll
  for (int i = 0; i < 4; i++) {
    #pragma unroll
    for (int r = 0; r < 4; r++) {
      int m = m0 + wm*64 + i*16 + quad*4 + r;
      if (m < cnt) {
        int p   = pbase + m;
        int tok = tof ? tof[p] : p;
        float sc2 = scale[p];
        #pragma unroll
        for (int j = 0; j < 4; j++) {
          int n = n0 + wn*64 + j*16 + l16;
          atomicAdd(&out[(size_t)tok * D_ + n], sc2 * acc[i][j][r]);
        }
      }
    }
  }
}

extern "C" void kernel_launch(void* const* d_in, const int* in_sizes, int n_in,
                              void* d_out, int out_size, void* d_ws, size_t ws_size,
                              hipStream_t stream) {
  const float* x      = (const float*)d_in[0];
  const float* gate_w = (const float*)d_in[1];
  const float* w_gate = (const float*)d_in[2];
  const float* w1     = (const float*)d_in[3];
  const float* w2     = (const float*)d_in[4];
  const float* sh_wg  = (const float*)d_in[5];
  const float* sh_w1  = (const float*)d_in[6];
  const float* sh_w2  = (const float*)d_in[7];
  const float* sh_gw  = (const float*)d_in[8];
  float* out = (float*)d_out;

  char* ws = (char*)d_ws;
  size_t off = 0;
  u16* xb    = (u16*)(ws + off); off += (size_t)NTOK * D_ * 2;
  u16* h_exp = (u16*)(ws + off); off += (size_t)NTOK * TOPK * H_ * 2;
  u16* h_sh  = (u16*)(ws + off); off += (size_t)NTOK * SH_ * 2;
  u16* wb_g  = (u16*)(ws + off); off += (size_t)E_ * H_ * D_ * 2;
  u16* wb_1  = (u16*)(ws + off); off += (size_t)E_ * H_ * D_ * 2;
  u16* wb_2  = (u16*)(ws + off); off += (size_t)E_ * D_ * H_ * 2;
  u16* sb_g  = (u16*)(ws + off); off += (size_t)SH_ * D_ * 2;
  u16* sb_1  = (u16*)(ws + off); off += (size_t)SH_ * D_ * 2;
  u16* sb_2  = (u16*)(ws + off); off += (size_t)D_ * SH_ * 2;
  int*   tok_of = (int*)  (ws + off); off += NTOK * TOPK * 4;
  float* w_of   = (float*)(ws + off); off += NTOK * TOPK * 4;
  float* sg     = (float*)(ws + off); off += NTOK * 4;
  int*   topk_e = (int*)  (ws + off); off += NTOK * TOPK * 4;
  float* topk_w = (float*)(ws + off); off += NTOK * TOPK * 4;
  int*   counts = (int*)  (ws + off); off += 64;
  int*   offs   = (int*)  (ws + off); off += 128;
  int*   fill   = (int*)  (ws + off); off += 64;
  int*   desc_e = (int*)  (ws + off); off += NDESC * 4;
  int*   desc_m = (int*)  (ws + off); off += NDESC * 4;

  hipMemsetAsync(counts, 0, 256, stream);            // counts + offs + fill
  hipMemsetAsync(out, 0, (size_t)NTOK * D_ * 4, stream);  // both downs atomic

  // cvt segment table (block counts = elems/1024)
  CvtTable ct;
  const float* srcs[7] = {x, w_gate, w1, w2, sh_wg, sh_w1, sh_w2};
  u16*         dsts[7] = {xb, wb_g, wb_1, wb_2, sb_g, sb_1, sb_2};
  int          nblk[7] = {NTOK*D_/1024, E_*H_*D_/1024, E_*H_*D_/1024,
                          E_*D_*H_/1024, SH_*D_/1024, SH_*D_/1024, D_*SH_/1024};
  int s = 0;
  for (int i = 0; i < 7; i++) { ct.src[i] = srcs[i]; ct.dst[i] = dsts[i];
                                ct.start[i] = s; s += nblk[i]; }
  ct.start[7] = s;

  cvtrouter_k<<<dim3(NRBLK + s), 256, 0, stream>>>(
      ct, x, gate_w, sh_gw, topk_e, topk_w, sg, counts);
  scan_scatter_k<<<dim3(1), 256, 0, stream>>>(
      counts, offs, desc_e, desc_m, topk_e, topk_w, fill, tok_of, w_of);

  up_merged<<<dim3(NSHUP + NRTUP), 256, 0, stream>>>(
      xb, sb_g, sb_1, h_sh, wb_g, wb_1, h_exp,
      tok_of, offs, counts, desc_e, desc_m);
  down_merged<<<dim3(NSHDN + NRTDN), 256, 0, stream>>>(
      h_sh, sb_2, sg, h_exp, wb_2, w_of, out,
      tok_of, offs, counts, desc_e, desc_m);

  (void)in_sizes; (void)n_in; (void)ws_size;
}

// Round 4
// 423.165 us; speedup vs baseline: 1.3174x; 1.0978x over previous
//
#include <hip/hip_runtime.h>
#include <stdint.h>

#define E_    16
#define TOPK  2
#define D_    1024
#define H_    1024
#define SH_   2048
#define NTOK  4096
#define BK    32      // K-step (u16 elements); tile rows are 64B
#define NDESC 80      // max expert chunks: 8192/128 + 16 partials
#define RTOK  16      // router tokens per block
#define NRBLK (NTOK / RTOK)         // 256 router blocks
#define NSHUP (NTOK/128 * SH_/128)  // 512 shared-up blocks (gy=16)
#define NRTUP (NDESC * H_/128)      // 640 routed-up blocks (gy=8)
#define NSHDN (NTOK/128 * D_/128)   // 256 shared-down blocks (gy=8)
#define NRTDN (NDESC * D_/128)      // 640 routed-down blocks (gy=8)
#define NUPGEMM (NSHUP + NRTUP)     // 1152 GEMM blocks in up_merged
#define NW2F4  (E_*D_*H_/4)         // 4,194,304 float4 in w2
#define NS2F4  (D_*SH_/4)           //   524,288 float4 in shared_w2
#define CVT2W2 (NW2F4/4096)         // 1024 cvt blocks (16 f4/thread)
#define CVT2S2 (NS2F4/4096)         //  128 cvt blocks
#define NCVT2  (CVT2W2 + CVT2S2)    // 1152 trailing cvt blocks in up_merged

typedef unsigned short u16;
typedef __attribute__((ext_vector_type(8))) __bf16 bf16x8;
typedef __attribute__((ext_vector_type(4))) float  f32x4;

struct CvtTable {
  const float* src[5];
  u16*         dst[5];
  int          start[6];   // block-range prefix over cvt blocks
};

__device__ __forceinline__ u16 f2bf(float f) {
  union { float f; unsigned int u; } v; v.f = f;
  unsigned int u = v.u;
  return (u16)((u + 0x7fffu + ((u >> 16) & 1u)) >> 16);   // RN-even
}

// async global->LDS, 16B per lane. LDS dest is wave-uniform base + lane*16
// (m104); global src is per-lane (m173) so gather is legal.
__device__ __forceinline__ void gload16(const void* g, void* l) {
  __builtin_amdgcn_global_load_lds(
      (const __attribute__((address_space(1))) unsigned int*)g,
      (__attribute__((address_space(3))) unsigned int*)l, 16, 0, 0);
}

// XCD-bijective swizzle over a 1D role range (nb % 8 == 0 for all our roles):
// XCD k owns a contiguous chunk of the role's linear block space.
__device__ __forceinline__ int swz8(int b, int nb) {
  return (b & 7) * (nb >> 3) + (b >> 3);
}

// ---------------- mega kernel 1: router blocks + pre-up fp32->bf16 cvt -----
// (x, w_gate, w1, shared_wg, shared_w1 -- the tensors up_merged needs)
__global__ __launch_bounds__(256) void cvtrouter_k(
    CvtTable ct,
    const float* __restrict__ x, const float* __restrict__ gate_w,
    const float* __restrict__ shared_gate_w,
    int* __restrict__ topk_e, float* __restrict__ topk_w,
    float* __restrict__ sg) {
  __shared__ float xs[RTOK][132];   // +4 pad: rows offset by 4 banks
  __shared__ float lg[RTOK][16];
  __shared__ float sgp[RTOK][16];

  int b   = blockIdx.x;
  int tid = threadIdx.x;

  if (b >= NRBLK) {
    // ---- cvt role: segmented streaming convert, one float4 per thread ----
    int cb = b - NRBLK;
    int s = 0;
    while (cb >= ct.start[s + 1]) s++;       // <=5 uniform iterations
    int i = (cb - ct.start[s]) * 256 + tid;
    float4 f = ((const float4*)ct.src[s])[i];
    ushort4 o; o.x = f2bf(f.x); o.y = f2bf(f.y); o.z = f2bf(f.z); o.w = f2bf(f.w);
    ((ushort4*)ct.dst[s])[i] = o;
    return;
  }

  // ---- router role: 16 tokens/block, thread=(expert,token), fp32 ----
  int e   = tid >> 4;               // 0..15
  int tt  = tid & 15;               // 0..15
  int t0  = b * RTOK;

  float acc = 0.f, sga = 0.f;
  for (int c = 0; c < D_; c += 128) {
    __syncthreads();                // xs reuse from previous chunk done
    #pragma unroll
    for (int i = 0; i < 2; i++) {
      int f = i * 256 + tid;        // 0..511 float4 units, fully coalesced
      int r = f >> 5, c4 = f & 31;
      *(float4*)&xs[r][c4 * 4] =
          *(const float4*)&x[(size_t)(t0 + r) * D_ + c + c4 * 4];
    }
    __syncthreads();
    const float* gw = &gate_w[(size_t)e * D_ + c];
    #pragma unroll
    for (int d4 = 0; d4 < 32; d4++) {
      float4 g  = *(const float4*)&gw[d4 * 4];
      float4 xv = *(const float4*)&xs[tt][d4 * 4];
      acc += xv.x * g.x + xv.y * g.y + xv.z * g.z + xv.w * g.w;
    }
    // shared-gate partial: this thread covers d in [e*8, e*8+8)
    #pragma unroll
    for (int j = 0; j < 8; j += 4) {
      float4 s2 = *(const float4*)&shared_gate_w[c + e * 8 + j];
      float4 xv = *(const float4*)&xs[tt][e * 8 + j];
      sga += xv.x * s2.x + xv.y * s2.y + xv.z * s2.z + xv.w * s2.w;
    }
  }
  lg[tt][e]  = acc;
  sgp[tt][e] = sga;
  __syncthreads();

  if (tid < RTOK) {
    int t = t0 + tid;
    float l[16];
    #pragma unroll
    for (int k = 0; k < 16; k++) l[k] = lg[tid][k];
    int i0 = 0; float l0 = l[0];
    for (int k = 1; k < 16; k++) if (l[k] > l0) { l0 = l[k]; i0 = k; }
    int i1 = -1; float l1 = -3.4e38f;
    for (int k = 0; k < 16; k++) if (k != i0 && l[k] > l1) { l1 = l[k]; i1 = k; }
    float w0 = 1.f / (1.f + expf(l1 - l0));   // == p0/(p0+p1)
    float s = 0.f;
    #pragma unroll
    for (int k = 0; k < 16; k++) s += sgp[tid][k];
    topk_e[2*t] = i0; topk_e[2*t+1] = i1;
    topk_w[2*t] = w0; topk_w[2*t+1] = 1.f - w0;
    sg[t] = 1.f / (1.f + expf(-s));
    // NOTE: no counts atomics -- scan_scatter_k histograms topk_e itself.
  }
}

// ---------------- zero-atomic scan + scatter, one block --------------------
// Per-thread LDS histogram (256x16) -> exclusive prefix per expert ->
// deterministic slot assignment. Replaces 16K contended atomics.
__global__ __launch_bounds__(256) void scan_scatter_k(
    const int* __restrict__ topk_e, const float* __restrict__ topk_w,
    int* __restrict__ counts, int* __restrict__ offs,
    int* __restrict__ desc_e, int* __restrict__ desc_m,
    int* __restrict__ tok_of, float* __restrict__ w_of) {
  __shared__ int hc[256][E_];      // 16 KB
  __shared__ int etot[E_];
  int tid = threadIdx.x;
  #pragma unroll
  for (int e = 0; e < E_; e++) hc[tid][e] = 0;
  __syncthreads();

  // count: thread tid owns tokens [tid*16, tid*16+16)
  for (int i = 0; i < 16; i++) {
    int t = tid * 16 + i;
    hc[tid][topk_e[2*t]]++;
    hc[tid][topk_e[2*t+1]]++;
  }
  __syncthreads();

  // exclusive prefix across tids, one thread per expert
  if (tid < E_) {
    int run = 0;
    for (int k = 0; k < 256; k++) { int c = hc[k][tid]; hc[k][tid] = run; run += c; }
    etot[tid] = run;
  }
  __syncthreads();

  if (tid == 0) {
    int s = 0, n = 0;
    for (int e = 0; e < E_; e++) {
      offs[e] = s; counts[e] = etot[e];
      for (int m0 = 0; m0 < etot[e]; m0 += 128) { desc_e[n] = e; desc_m[n] = m0; n++; }
      s += etot[e];
    }
    offs[E_] = s;
    for (; n < NDESC; n++) { desc_e[n] = -1; desc_m[n] = 0; }
  }
  __syncthreads();

  // scatter: replay tokens; hc[tid][e] is now this thread's running base
  for (int i = 0; i < 16; i++) {
    int t = tid * 16 + i;
    #pragma unroll
    for (int k = 0; k < TOPK; k++) {
      int e = topk_e[2*t+k];
      int p = hc[tid][e]++;
      int slot = offs[e] + p;
      tok_of[slot] = t;
      w_of[slot]   = topk_w[2*t+k];
    }
  }
}

// ---------------- merged up-projection + W2 cvt tail -----------------------
// GEMM roles: h = (x@W1^T) * silu(x@Wg^T), counted-vmcnt depth-2 pipeline.
// Trailing 1152 blocks stream-convert w2 / shared_w2 (needed only by down,
// which launches after) -- they fill the GEMM tail's idle CUs.
__global__ __launch_bounds__(256, 2) void up_merged(
    const u16* __restrict__ Xb,
    const u16* __restrict__ sWg, const u16* __restrict__ sW1, u16* __restrict__ sHout,
    const u16* __restrict__ rWg_all, const u16* __restrict__ rW1_all, u16* __restrict__ rHout,
    const float* __restrict__ w2f, u16* __restrict__ wb2,
    const float* __restrict__ s2f, u16* __restrict__ sb2,
    const int* __restrict__ tok_of,
    const int* __restrict__ offs, const int* __restrict__ counts,
    const int* __restrict__ desc_e, const int* __restrict__ desc_m) {
  int bid = blockIdx.x;
  if (bid >= NUPGEMM) {
    // ---- cvt role: 16 float4 per thread, fully coalesced ----
    int cb = bid - NUPGEMM;
    const float4* src; ushort4* dst; int base;
    if (cb < CVT2W2) { src = (const float4*)w2f; dst = (ushort4*)wb2; base = cb * 4096; }
    else             { src = (const float4*)s2f; dst = (ushort4*)sb2; base = (cb - CVT2W2) * 4096; }
    int tid = threadIdx.x;
    #pragma unroll
    for (int i = 0; i < 16; i++) {
      int idx = base + i * 256 + tid;
      float4 f = src[idx];
      ushort4 o; o.x = f2bf(f.x); o.y = f2bf(f.y); o.z = f2bf(f.z); o.w = f2bf(f.w);
      dst[idx] = o;
    }
    return;
  }

  const u16 *Wg, *W1; u16* Hout; int Hdim;
  int m0, cnt, pbase, n0;
  const int* tof;
  if (bid < NSHUP) {                        // shared-expert role (gy = 16)
    int l = swz8(bid, NSHUP);
    int bx = l >> 4, by = l & 15;
    m0 = bx * 128; cnt = NTOK; pbase = 0; tof = nullptr;
    Wg = sWg; W1 = sW1; Hout = sHout; Hdim = SH_;
    n0 = by * 128;
  } else {                                  // routed role (gy = 8)
    int r = bid - NSHUP;
    int l = swz8(r, NRTUP);
    int bx = l >> 3, by = l & 7;
    int e = desc_e[bx];
    if (e < 0) return;
    m0 = desc_m[bx]; cnt = counts[e]; pbase = offs[e]; tof = tok_of;
    Wg = rWg_all + (size_t)e * H_ * D_;
    W1 = rW1_all + (size_t)e * H_ * D_;
    Hout = rHout; Hdim = H_;
    n0 = by * 128;
  }

  __shared__ u16 smem[2 * 3 * 4096];   // [buf][A,G,U][128*BK]  48KB

  int tid  = threadIdx.x;
  int lane = tid & 63, wave = tid >> 6;
  int wm = wave & 1, wn = wave >> 1;
  int l16 = lane & 15, quad = lane >> 4;

  // staging: wave w owns rows [w*16, w*16+16) (+64 for 2nd issue); lane l
  // lands at wave_base + l*16 bytes = row w*16 + l/4, col (l&3)*8 elems.
  int sr = wave * 16 + (lane >> 2);
  int sc = (lane & 3) * 8;

  int gm0 = m0 + sr;      if (gm0 >= cnt) gm0 = cnt - 1;
  int gm1 = m0 + sr + 64; if (gm1 >= cnt) gm1 = cnt - 1;
  int tok0 = tof ? tof[pbase + gm0] : gm0;
  int tok1 = tof ? tof[pbase + gm1] : gm1;
  const u16* pa0 = Xb + (size_t)tok0 * D_ + sc;
  const u16* pa1 = Xb + (size_t)tok1 * D_ + sc;
  const u16* pg0 = Wg + (size_t)(n0 + sr) * D_ + sc;
  const u16* pg1 = pg0 + (size_t)64 * D_;
  const u16* pu0 = W1 + (size_t)(n0 + sr) * D_ + sc;
  const u16* pu1 = pu0 + (size_t)64 * D_;

  int lbase = wave * 512;   // u16 units: wave*1024B within a tile

  f32x4 accg[4][4], accu[4][4];
  f32x4 zero = {0.f, 0.f, 0.f, 0.f};
  #pragma unroll
  for (int i = 0; i < 4; i++)
    #pragma unroll
    for (int j = 0; j < 4; j++) { accg[i][j] = zero; accu[i][j] = zero; }

#define STAGE_UP(b) do {                                            \
    u16* s_ = smem + (b) * 12288 + lbase;                           \
    gload16(pa0, s_);        gload16(pa1, s_ + 2048);               \
    gload16(pg0, s_ + 4096); gload16(pg1, s_ + 6144);               \
    gload16(pu0, s_ + 8192); gload16(pu1, s_ + 10240);              \
    pa0 += BK; pa1 += BK; pg0 += BK; pg1 += BK; pu0 += BK; pu1 += BK; \
  } while (0)

  STAGE_UP(0);                      // tile 0   (6 loads in flight)
  STAGE_UP(1);                      // tile 1   (12 in flight)
  int buf = 0;
  const int nt = D_ / BK;           // 32

  for (int t = 0; t < nt; ++t) {
    if (t + 1 < nt) asm volatile("s_waitcnt vmcnt(6)" ::: "memory");
    else            asm volatile("s_waitcnt vmcnt(0)" ::: "memory");
    __builtin_amdgcn_s_barrier();          // tile t complete in LDS, all waves
    __builtin_amdgcn_sched_barrier(0);     // rule #18: no hoist above barrier

    const u16* base = smem + buf * 12288;
    bf16x8 af[4], gf[4], uf[4];
    #pragma unroll
    for (int i = 0; i < 4; i++) {
      af[i] = *(const bf16x8*)&base[(wm*64 + i*16 + l16)*BK + quad*8];
      gf[i] = *(const bf16x8*)&base[4096 + (wn*64 + i*16 + l16)*BK + quad*8];
      uf[i] = *(const bf16x8*)&base[8192 + (wn*64 + i*16 + l16)*BK + quad*8];
    }
    #pragma unroll
    for (int i = 0; i < 4; i++)
      #pragma unroll
      for (int j = 0; j < 4; j++) {
        accg[i][j] = __builtin_amdgcn_mfma_f32_16x16x32_bf16(af[i], gf[j], accg[i][j], 0, 0, 0);
        accu[i][j] = __builtin_amdgcn_mfma_f32_16x16x32_bf16(af[i], uf[j], accu[i][j], 0, 0, 0);
      }

    __builtin_amdgcn_sched_barrier(0);     // reads stay above barrier #2
    __builtin_amdgcn_s_barrier();          // all waves done reading buf
    if (t + 2 < nt) STAGE_UP(buf);         // tile t+2 -> just-freed buffer
    buf ^= 1;
  }
#undef STAGE_UP

  // epilogue: h = u * silu(g)  (C/D map: col=lane&15, row=quad*4+reg — verified)
  #pragma unroll
  for (int i = 0; i < 4; i++) {
    #pragma unroll
    for (int r = 0; r < 4; r++) {
      int m = m0 + wm*64 + i*16 + quad*4 + r;
      if (m < cnt) {
        size_t prow = (size_t)(pbase + m) * Hdim;
        #pragma unroll
        for (int j = 0; j < 4; j++) {
          int n = n0 + wn*64 + j*16 + l16;
          float g = accg[i][j][r];
          float u = accu[i][j][r];
          Hout[prow + n] = f2bf(u * (g / (1.f + expf(-g))));
        }
      }
    }
  }
}

// ---------------- merged down-projection: shared + routed, both atomic -----
// out[tok] += scale * (h @ W2^T); out pre-zeroed by memset.
__global__ __launch_bounds__(256, 3) void down_merged(
    const u16* __restrict__ sHbuf, const u16* __restrict__ sW2, const float* __restrict__ sg,
    const u16* __restrict__ rHbuf, const u16* __restrict__ rW2_all, const float* __restrict__ w_of,
    float* __restrict__ out,
    const int* __restrict__ tok_of,
    const int* __restrict__ offs, const int* __restrict__ counts,
    const int* __restrict__ desc_e, const int* __restrict__ desc_m) {
  int bid = blockIdx.x;
  const u16 *Hbuf, *W2; const float* scale;
  int m0, cnt, pbase, n0, K;
  const int* tof;
  if (bid < NSHDN) {                        // shared role: K = SH_ (gy = 8)
    int l = swz8(bid, NSHDN);
    int bx = l >> 3, by = l & 7;
    m0 = bx * 128; cnt = NTOK; pbase = 0; tof = nullptr;
    Hbuf = sHbuf; W2 = sW2; scale = sg; K = SH_;
    n0 = by * 128;
  } else {                                  // routed role: K = H_ (gy = 8)
    int r = bid - NSHDN;
    int l = swz8(r, NRTDN);
    int bx = l >> 3, by = l & 7;
    int e = desc_e[bx];
    if (e < 0) return;
    m0 = desc_m[bx]; cnt = counts[e]; pbase = offs[e]; tof = tok_of;
    Hbuf = rHbuf; W2 = rW2_all + (size_t)e * D_ * H_; scale = w_of; K = H_;
    n0 = by * 128;
  }

  __shared__ u16 smem[2 * 2 * 4096];   // [buf][A,B][128*BK]  32KB

  int tid  = threadIdx.x;
  int lane = tid & 63, wave = tid >> 6;
  int wm = wave & 1, wn = wave >> 1;
  int l16 = lane & 15, quad = lane >> 4;

  int sr = wave * 16 + (lane >> 2);
  int sc = (lane & 3) * 8;

  int gm0 = m0 + sr;      if (gm0 >= cnt) gm0 = cnt - 1;
  int gm1 = m0 + sr + 64; if (gm1 >= cnt) gm1 = cnt - 1;
  const u16* pa0 = Hbuf + (size_t)(pbase + gm0) * K + sc;
  const u16* pa1 = Hbuf + (size_t)(pbase + gm1) * K + sc;
  const u16* pb0 = W2 + (size_t)(n0 + sr) * K + sc;
  const u16* pb1 = pb0 + (size_t)64 * K;

  int lbase = wave * 512;

  f32x4 acc[4][4];
  f32x4 zero = {0.f, 0.f, 0.f, 0.f};
  #pragma unroll
  for (int i = 0; i < 4; i++)
    #pragma unroll
    for (int j = 0; j < 4; j++) acc[i][j] = zero;

#define STAGE_DN(b) do {                                \
    u16* s_ = smem + (b) * 8192 + lbase;                \
    gload16(pa0, s_);        gload16(pa1, s_ + 2048);   \
    gload16(pb0, s_ + 4096); gload16(pb1, s_ + 6144);   \
    pa0 += BK; pa1 += BK; pb0 += BK; pb1 += BK;         \
  } while (0)

  STAGE_DN(0);                      // tile 0
  STAGE_DN(1);                      // tile 1
  int buf = 0;
  const int nt = K / BK;

  for (int t = 0; t < nt; ++t) {
    if (t + 1 < nt) asm volatile("s_waitcnt vmcnt(4)" ::: "memory");
    else            asm volatile("s_waitcnt vmcnt(0)" ::: "memory");
    __builtin_amdgcn_s_barrier();
    __builtin_amdgcn_sched_barrier(0);

    const u16* base = smem + buf * 8192;
    bf16x8 af[4], bfr[4];
    #pragma unroll
    for (int i = 0; i < 4; i++) {
      af[i]  = *(const bf16x8*)&base[(wm*64 + i*16 + l16)*BK + quad*8];
      bfr[i] = *(const bf16x8*)&base[4096 + (wn*64 + i*16 + l16)*BK + quad*8];
    }
    #pragma unroll
    for (int i = 0; i < 4; i++)
      #pragma unroll
      for (int j = 0; j < 4; j++)
        acc[i][j] = __builtin_amdgcn_mfma_f32_16x16x32_bf16(af[i], bfr[j], acc[i][j], 0, 0, 0);

    __builtin_amdgcn_sched_barrier(0);
    __builtin_amdgcn_s_barrier();
    if (t + 2 < nt) STAGE_DN(buf);
    buf ^= 1;
  }
#undef STAGE_DN

  #pragma unroll
  for (int i = 0; i < 4; i++) {
    #pragma unroll
    for (int r = 0; r < 4; r++) {
      int m = m0 + wm*64 + i*16 + quad*4 + r;
      if (m < cnt) {
        int p   = pbase + m;
        int tok = tof ? tof[p] : p;
        float sc2 = scale[p];
        #pragma unroll
        for (int j = 0; j < 4; j++) {
          int n = n0 + wn*64 + j*16 + l16;
          atomicAdd(&out[(size_t)tok * D_ + n], sc2 * acc[i][j][r]);
        }
      }
    }
  }
}

extern "C" void kernel_launch(void* const* d_in, const int* in_sizes, int n_in,
                              void* d_out, int out_size, void* d_ws, size_t ws_size,
                              hipStream_t stream) {
  const float* x      = (const float*)d_in[0];
  const float* gate_w = (const float*)d_in[1];
  const float* w_gate = (const float*)d_in[2];
  const float* w1     = (const float*)d_in[3];
  const float* w2     = (const float*)d_in[4];
  const float* sh_wg  = (const float*)d_in[5];
  const float* sh_w1  = (const float*)d_in[6];
  const float* sh_w2  = (const float*)d_in[7];
  const float* sh_gw  = (const float*)d_in[8];
  float* out = (float*)d_out;

  char* ws = (char*)d_ws;
  size_t off = 0;
  u16* xb    = (u16*)(ws + off); off += (size_t)NTOK * D_ * 2;
  u16* h_exp = (u16*)(ws + off); off += (size_t)NTOK * TOPK * H_ * 2;
  u16* h_sh  = (u16*)(ws + off); off += (size_t)NTOK * SH_ * 2;
  u16* wb_g  = (u16*)(ws + off); off += (size_t)E_ * H_ * D_ * 2;
  u16* wb_1  = (u16*)(ws + off); off += (size_t)E_ * H_ * D_ * 2;
  u16* wb_2  = (u16*)(ws + off); off += (size_t)E_ * D_ * H_ * 2;
  u16* sb_g  = (u16*)(ws + off); off += (size_t)SH_ * D_ * 2;
  u16* sb_1  = (u16*)(ws + off); off += (size_t)SH_ * D_ * 2;
  u16* sb_2  = (u16*)(ws + off); off += (size_t)D_ * SH_ * 2;
  int*   tok_of = (int*)  (ws + off); off += NTOK * TOPK * 4;
  float* w_of   = (float*)(ws + off); off += NTOK * TOPK * 4;
  float* sg     = (float*)(ws + off); off += NTOK * 4;
  int*   topk_e = (int*)  (ws + off); off += NTOK * TOPK * 4;
  float* topk_w = (float*)(ws + off); off += NTOK * TOPK * 4;
  int*   counts = (int*)  (ws + off); off += 64;
  int*   offs   = (int*)  (ws + off); off += 128;
  int*   fill   = (int*)  (ws + off); off += 64;   // unused (kept for layout)
  int*   desc_e = (int*)  (ws + off); off += NDESC * 4;
  int*   desc_m = (int*)  (ws + off); off += NDESC * 4;

  hipMemsetAsync(out, 0, (size_t)NTOK * D_ * 4, stream);  // both downs atomic

  // cvt segment table: only what up_merged needs (w2/sh_w2 ride in up_merged)
  CvtTable ct;
  const float* srcs[5] = {x, w_gate, w1, sh_wg, sh_w1};
  u16*         dsts[5] = {xb, wb_g, wb_1, sb_g, sb_1};
  int          nblk[5] = {NTOK*D_/1024, E_*H_*D_/1024, E_*H_*D_/1024,
                          SH_*D_/1024, SH_*D_/1024};
  int s = 0;
  for (int i = 0; i < 5; i++) { ct.src[i] = srcs[i]; ct.dst[i] = dsts[i];
                                ct.start[i] = s; s += nblk[i]; }
  ct.start[5] = s;

  cvtrouter_k<<<dim3(NRBLK + s), 256, 0, stream>>>(
      ct, x, gate_w, sh_gw, topk_e, topk_w, sg);
  scan_scatter_k<<<dim3(1), 256, 0, stream>>>(
      topk_e, topk_w, counts, offs, desc_e, desc_m, tok_of, w_of);

  up_merged<<<dim3(NUPGEMM + NCVT2), 256, 0, stream>>>(
      xb, sb_g, sb_1, h_sh, wb_g, wb_1, h_exp,
      w2, wb_2, sh_w2, sb_2,
      tok_of, offs, counts, desc_e, desc_m);
  down_merged<<<dim3(NSHDN + NRTDN), 256, 0, stream>>>(
      h_sh, sb_2, sg, h_exp, wb_2, w_of, out,
      tok_of, offs, counts, desc_e, desc_m);

  (void)in_sizes; (void)n_in; (void)ws_size; (void)fill;
}